// Round 4
// baseline (3431.480 us; speedup 1.0000x reference)
//
#include <hip/hip_runtime.h>
#include <hip/hip_cooperative_groups.h>

namespace cg = cooperative_groups;

#define NN    50000
#define RR    4
#define DDEP  5
#define NIN   17400
#define BB    2
#define TT    50
#define EREC  2000000
#define EIN   500000
#define RNN   (RR*NN)    // 200000
#define DNN   (DDEP*NN)  // 250000
#define RING  6
#define SCAN_TPB 256
#define SCAN_ITEMS 4

struct SP {
  const float* x; const float* bkg;
  const float* v_th; const float* e_l; const float* v_reset; const float* g;
  const float* t_ref; const float* asc_amps; const float* param_k;
  const float* decay; const float* cf; const float* syn_decay; const float* psc_init;
  const float* vscale; const float* voff;
  const int* rest;
  float* out_z; float* out_v;
  float* cur_ring;      // ws: [BB][RING][RNN] future-accumulator ring
  int*   flags;         // ws: [BB][RING] epoch tags (target step) for dirty check
  const int* row_ptr;   // ws: [RNN+1]  input CSR (by target row)
  const int2* cw_in;    // ws: [EIN]   {col, w-bits}
  const int* col_ptr;   // ws: [DNN+1]  rec CSC (by source col = d*NN+src)
  const int2* cw_rec;   // ws: [EREC]  {row, w-bits}
};

// ---------- fused histogram ----------
__global__ void hist2_k(const int* __restrict__ in_rows, const int* __restrict__ rec_cols,
                        int* __restrict__ cnt_in, int* __restrict__ cnt_rec) {
  int i = blockIdx.x * blockDim.x + threadIdx.x;
  int nth = gridDim.x * blockDim.x;
  for (int e = i; e < EIN + EREC; e += nth) {
    if (e < EIN) atomicAdd(&cnt_in[in_rows[e]], 1);
    else         atomicAdd(&cnt_rec[rec_cols[e - EIN]], 1);
  }
}

// ---------- 3-phase exclusive scan ----------
__global__ __launch_bounds__(SCAN_TPB) void blocksum_k(const int* __restrict__ cnt, int n,
                                                       int* __restrict__ partial) {
  __shared__ int sm[SCAN_TPB];
  int base = (blockIdx.x * SCAN_TPB + threadIdx.x) * SCAN_ITEMS;
  int s = 0;
  #pragma unroll
  for (int j = 0; j < SCAN_ITEMS; ++j) { int idx = base + j; if (idx < n) s += cnt[idx]; }
  sm[threadIdx.x] = s; __syncthreads();
  for (int off = SCAN_TPB / 2; off > 0; off >>= 1) {
    if (threadIdx.x < off) sm[threadIdx.x] += sm[threadIdx.x + off];
    __syncthreads();
  }
  if (threadIdx.x == 0) partial[blockIdx.x] = sm[0];
}

__global__ __launch_bounds__(SCAN_TPB) void scanpart_k(int* __restrict__ partial, int nb) {
  __shared__ int sm[SCAN_TPB];
  int i = threadIdx.x;
  int v = (i < nb) ? partial[i] : 0;
  sm[i] = v; __syncthreads();
  for (int off = 1; off < SCAN_TPB; off <<= 1) {
    int a = (i >= off) ? sm[i - off] : 0;
    __syncthreads();
    sm[i] += a;
    __syncthreads();
  }
  if (i < nb) partial[i] = sm[i] - v;   // exclusive
}

__global__ __launch_bounds__(SCAN_TPB) void finalize_k(const int* __restrict__ cnt, int n,
                                                       const int* __restrict__ partial,
                                                       int* __restrict__ ptr,
                                                       int* __restrict__ cursor, int nE) {
  __shared__ int sm[SCAN_TPB];
  int tidl = threadIdx.x;
  int base = (blockIdx.x * SCAN_TPB + tidl) * SCAN_ITEMS;
  int local[SCAN_ITEMS];
  int s = 0;
  #pragma unroll
  for (int j = 0; j < SCAN_ITEMS; ++j) {
    int idx = base + j;
    int c = (idx < n) ? cnt[idx] : 0;
    local[j] = c; s += c;
  }
  sm[tidl] = s; __syncthreads();
  for (int off = 1; off < SCAN_TPB; off <<= 1) {
    int a = (tidl >= off) ? sm[tidl - off] : 0;
    __syncthreads();
    sm[tidl] += a;
    __syncthreads();
  }
  int run = partial[blockIdx.x] + sm[tidl] - s;   // exclusive offset for this thread
  #pragma unroll
  for (int j = 0; j < SCAN_ITEMS; ++j) {
    int idx = base + j;
    if (idx < n) { ptr[idx] = run; cursor[idx] = run; run += local[j]; }
  }
  if (blockIdx.x == 0 && tidl == 0) ptr[n] = nE;
}

// ---------- fused scatter (build CSR payload {col,w} / CSC payload {row,w}) ----------
__global__ void scatter2_k(const int* __restrict__ in_rows, const int* __restrict__ in_cols,
                           const float* __restrict__ in_w,
                           const int* __restrict__ rec_cols, const int* __restrict__ rec_rows,
                           const float* __restrict__ rec_w,
                           int* __restrict__ cur_in, int* __restrict__ cur_rec,
                           int2* __restrict__ cw_in, int2* __restrict__ cw_rec) {
  int i = blockIdx.x * blockDim.x + threadIdx.x;
  int nth = gridDim.x * blockDim.x;
  for (int e = i; e < EIN + EREC; e += nth) {
    if (e < EIN) {
      int pos = atomicAdd(&cur_in[in_rows[e]], 1);
      cw_in[pos] = make_int2(in_cols[e], __float_as_int(in_w[e]));
    } else {
      int ee = e - EIN;
      int pos = atomicAdd(&cur_rec[rec_cols[ee]], 1);
      cw_rec[pos] = make_int2(rec_rows[ee], __float_as_int(rec_w[ee]));
    }
  }
}

// ---------- main persistent kernel ----------
__global__ __launch_bounds__(256, 2) void snn_all(SP p) {
  cg::grid_group grid = cg::this_grid();
  const int tid = blockIdx.x * blockDim.x + threadIdx.x;

  const bool owner = tid < BB * NN;
  int b = 0, n = 0;
  float sd[RR], pi[RR], bkgv[RR], psc_rise[RR], psc[RR];
  int rbeg[RR], rend[RR];
  float v = 0.f, refr = 0.f, a1 = 0.f, a2 = 0.f, my_z = 0.f;
  float dcy = 0.f, cfac = 0.f, trf = 0.f, amp1 = 0.f, amp2 = 0.f;
  float ad1 = 0.f, ad2 = 0.f, vth = 0.f, invn = 0.f, leak = 0.f;
  float vrst = 0.f, vsc = 0.f, vof = 0.f;
  #pragma unroll
  for (int r = 0; r < RR; ++r) {
    sd[r]=0.f; pi[r]=0.f; bkgv[r]=0.f; psc_rise[r]=0.f; psc[r]=0.f;
    rbeg[r]=0; rend[r]=0;
  }

  if (owner) {
    b = (tid >= NN) ? 1 : 0;
    n = tid - b * NN;
    #pragma unroll
    for (int r = 0; r < RR; ++r) {
      sd[r]   = p.syn_decay[n*RR + r];
      pi[r]   = p.psc_init[n*RR + r];
      bkgv[r] = p.bkg[n*RR + r];
      rbeg[r] = p.row_ptr[n*RR + r];
      rend[r] = p.row_ptr[n*RR + r + 1];
    }
    vth  = p.v_th[n];
    float el = p.e_l[n];
    invn = 1.0f / (vth - el);
    leak = p.g[n] * el;
    vrst = p.v_reset[n];
    v    = vrst;
    dcy  = p.decay[n];
    cfac = p.cf[n];
    trf  = p.t_ref[n];
    amp1 = p.asc_amps[2*n+0];
    amp2 = p.asc_amps[2*n+1];
    ad1  = expf(-p.param_k[2*n+0]);
    ad2  = expf(-p.param_k[2*n+1]);
    vsc  = p.vscale[n];
    vof  = p.voff[n];
  }
  const float* xb = p.x + (size_t)b * TT * NIN;
  float* ringB = p.cur_ring + (size_t)b * RING * RNN;

  for (int t = 0; t < TT; ++t) {
    if (t) grid.sync();   // ring pushes + flags from step t-1 now visible

    if (owner) {
      float restf = (float)p.rest[t*BB + b] * 0.1f;
      const float* xt = xb + (size_t)t * NIN;
      int slot = t % RING;

      float rin[RR] = { 0.f, 0.f, 0.f, 0.f };
      // recurrent ring slot: read+zero only when epoch tag says someone pushed here
      if (p.flags[b*RING + slot] == t) {
        float4* slotR = (float4*)(ringB + (size_t)slot * RNN);
        float4 rv = slotR[n];
        slotR[n] = make_float4(0.f, 0.f, 0.f, 0.f);   // reused at step t+RING
        rin[0] = rv.x; rin[1] = rv.y; rin[2] = rv.z; rin[3] = rv.w;
      }

      // input gather (CSR, interleaved {col,w}) + background
      #pragma unroll
      for (int r = 0; r < RR; ++r) {
        float acc = bkgv[r] * restf;
        for (int e = rbeg[r]; e < rend[r]; ++e) {
          int2 cw = p.cw_in[e];
          acc += xt[cw.x] * __int_as_float(cw.y);
        }
        rin[r] += acc;
      }

      float prev_z = my_z;
      float input_current = psc[0] + psc[1] + psc[2] + psc[3];   // OLD psc
      float new_v = dcy * v + cfac * (input_current + a1 + a2 + leak)
                    + prev_z * (vrst - vth);
      #pragma unroll
      for (int r = 0; r < RR; ++r) {       // new_psc uses OLD psc_rise
        float npsc = psc[r] * sd[r] + sd[r] * psc_rise[r];
        psc_rise[r] = sd[r] * psc_rise[r] + rin[r] * pi[r];
        psc[r] = npsc;
      }
      refr = fmaxf(refr + prev_z * trf - 1.0f, 0.f);
      a1 = ad1 * a1 + prev_z * amp1;
      a2 = ad2 * a2 + prev_z * amp2;
      v = new_v;
      float v_scaled = (new_v - vth) * invn;
      float z = (v_scaled > 0.f) ? 1.f : 0.f;
      if (refr > 0.f) z = 0.f;
      my_z = z;
      size_t oidx = (size_t)b * (TT*NN) + (size_t)t * NN + n;
      p.out_z[oidx] = z;
      p.out_v[oidx] = new_v * vsc + vof;

      // event-driven scatter: push outgoing edges into future ring slots
      if (z != 0.f) {
        #pragma unroll
        for (int d = 0; d < DDEP; ++d) {
          int tt = t + 1 + d;
          if (tt >= TT) break;
          int col = d * NN + n;
          int be = p.col_ptr[col], en = p.col_ptr[col + 1];
          if (be != en) {
            int ws_ = tt % RING;
            p.flags[b*RING + ws_] = tt;   // benign same-value race; fenced by grid.sync
            float* ringW = ringB + (size_t)ws_ * RNN;
            for (int e = be; e < en; ++e) {
              int2 cw = p.cw_rec[e];
              atomicAdd(&ringW[cw.x], __int_as_float(cw.y));
            }
          }
        }
      }
    }
  }
}

extern "C" void kernel_launch(void* const* d_in, const int* in_sizes, int n_in,
                              void* d_out, int out_size, void* d_ws, size_t ws_size,
                              hipStream_t stream) {
  SP p;
  p.x        = (const float*)d_in[0];
  const float* rec_w = (const float*)d_in[1];
  const float* in_w  = (const float*)d_in[2];
  p.bkg      = (const float*)d_in[3];
  p.v_th     = (const float*)d_in[4];
  p.e_l      = (const float*)d_in[5];
  p.v_reset  = (const float*)d_in[6];
  p.g        = (const float*)d_in[7];
  p.t_ref    = (const float*)d_in[8];
  p.asc_amps = (const float*)d_in[9];
  p.param_k  = (const float*)d_in[10];
  p.decay    = (const float*)d_in[11];
  p.cf       = (const float*)d_in[12];
  p.syn_decay= (const float*)d_in[13];
  p.psc_init = (const float*)d_in[14];
  p.vscale   = (const float*)d_in[15];
  p.voff     = (const float*)d_in[16];
  const int* rec_rows = (const int*)d_in[17];
  const int* rec_cols = (const int*)d_in[18];
  const int* in_rows  = (const int*)d_in[19];
  const int* in_cols  = (const int*)d_in[20];
  p.rest     = (const int*)d_in[21];
  p.out_z = (float*)d_out;
  p.out_v = (float*)d_out + (size_t)BB * TT * NN;

  // ---- workspace layout ----
  char* ws = (char*)d_ws;
  size_t off = 0;
  auto alloc = [&](size_t bytes) { void* q = ws + off; off += (bytes + 255) & ~(size_t)255; return q; };
  float* cur_ring = (float*)alloc(sizeof(float) * (size_t)BB * RING * RNN); // 9.6 MB
  int*   flags    = (int*)  alloc(sizeof(int) * BB * RING);                 // 48 B
  int*   row_ptr  = (int*)  alloc(sizeof(int) * ((size_t)RNN + 1));
  int*   col_ptr  = (int*)  alloc(sizeof(int) * ((size_t)DNN + 1));
  int*   cnt_in   = (int*)  alloc(sizeof(int) * (size_t)RNN);               // contiguous with
  int*   cnt_rec  = (int*)  (ws + off - ((sizeof(int)*(size_t)DNN + 255) & ~(size_t)255) * 0); // placeholder
  cnt_rec         = (int*)  alloc(sizeof(int) * (size_t)DNN);               // cnt_rec right after cnt_in? (see memset below)
  int*   cur_in   = (int*)  alloc(sizeof(int) * (size_t)RNN);
  int*   cur_rec  = (int*)  alloc(sizeof(int) * (size_t)DNN);
  int*   part_in  = (int*)  alloc(sizeof(int) * SCAN_TPB);
  int*   part_rec = (int*)  alloc(sizeof(int) * SCAN_TPB);
  int2*  cw_in    = (int2*) alloc(sizeof(int2) * (size_t)EIN);              // 4 MB
  int2*  cw_rec   = (int2*) alloc(sizeof(int2) * (size_t)EREC);             // 16 MB

  p.cur_ring = cur_ring; p.flags = flags;
  p.row_ptr = row_ptr; p.cw_in = cw_in;
  p.col_ptr = col_ptr; p.cw_rec = cw_rec;

  hipMemsetAsync(cur_ring, 0, sizeof(float) * (size_t)BB * RING * RNN, stream);
  hipMemsetAsync(flags, 0xFF, sizeof(int) * BB * RING, stream);            // -1 epochs
  hipMemsetAsync(cnt_in, 0, sizeof(int) * (size_t)RNN, stream);
  hipMemsetAsync(cnt_rec, 0, sizeof(int) * (size_t)DNN, stream);

  hipLaunchKernelGGL(hist2_k, dim3(1024), dim3(256), 0, stream,
                     in_rows, rec_cols, cnt_in, cnt_rec);

  const int NB_IN  = (RNN + SCAN_TPB * SCAN_ITEMS - 1) / (SCAN_TPB * SCAN_ITEMS);  // 196
  const int NB_REC = (DNN + SCAN_TPB * SCAN_ITEMS - 1) / (SCAN_TPB * SCAN_ITEMS);  // 245
  hipLaunchKernelGGL(blocksum_k, dim3(NB_IN),  dim3(SCAN_TPB), 0, stream, cnt_in,  RNN, part_in);
  hipLaunchKernelGGL(blocksum_k, dim3(NB_REC), dim3(SCAN_TPB), 0, stream, cnt_rec, DNN, part_rec);
  hipLaunchKernelGGL(scanpart_k, dim3(1), dim3(SCAN_TPB), 0, stream, part_in,  NB_IN);
  hipLaunchKernelGGL(scanpart_k, dim3(1), dim3(SCAN_TPB), 0, stream, part_rec, NB_REC);
  hipLaunchKernelGGL(finalize_k, dim3(NB_IN),  dim3(SCAN_TPB), 0, stream, cnt_in,  RNN, part_in,  row_ptr, cur_in,  EIN);
  hipLaunchKernelGGL(finalize_k, dim3(NB_REC), dim3(SCAN_TPB), 0, stream, cnt_rec, DNN, part_rec, col_ptr, cur_rec, EREC);

  hipLaunchKernelGGL(scatter2_k, dim3(1024), dim3(256), 0, stream,
                     in_rows, in_cols, in_w, rec_cols, rec_rows, rec_w,
                     cur_in, cur_rec, cw_in, cw_rec);

  void* args[] = { (void*)&p };
  hipLaunchCooperativeKernel(reinterpret_cast<const void*>(&snn_all),
                             dim3(400), dim3(256), args, 0u, stream);
}

// Round 5
// 1418.685 us; speedup vs baseline: 2.4188x; 2.4188x over previous
//
#include <hip/hip_runtime.h>
#include <hip/hip_cooperative_groups.h>

namespace cg = cooperative_groups;

#define NN    50000
#define RR    4
#define DDEP  5
#define NIN   17400
#define BB    2
#define TT    50
#define EREC  2000000
#define EIN   500000
#define RNN   (RR*NN)    // 200000
#define DNN   (DDEP*NN)  // 250000
#define RING  6
#define SCAN_TPB 256
#define SCAN_ITEMS 4

struct SP {
  const float* x; const float* bkg;
  const float* v_th; const float* e_l; const float* v_reset; const float* g;
  const float* t_ref; const float* asc_amps; const float* param_k;
  const float* decay; const float* cf; const float* syn_decay; const float* psc_init;
  const float* vscale; const float* voff;
  const int* rest;
  float* out_z; float* out_v;
  float* cur_ring;      // ws: [BB][RING][RNN] future-accumulator ring
  int*   flags;         // ws: [BB][RING] epoch tags (target step)
  const int* row_ptr;   // ws: [RNN+1]  input CSR (by target row)
  const int2* cw_in;    // ws: [EIN]   {col, w-bits}
  const int* col_ptr;   // ws: [DNN+1]  rec CSC (by source col = d*NN+src)
  const int2* cw_rec;   // ws: [EREC]  {row, w-bits}
  const float* in_cur;  // ws: [TT*BB][RNN] precomputed input+bkg currents (or nullptr)
};

// ---------- fused histogram ----------
__global__ void hist2_k(const int* __restrict__ in_rows, const int* __restrict__ rec_cols,
                        int* __restrict__ cnt_in, int* __restrict__ cnt_rec) {
  int i = blockIdx.x * blockDim.x + threadIdx.x;
  int nth = gridDim.x * blockDim.x;
  for (int e = i; e < EIN + EREC; e += nth) {
    if (e < EIN) atomicAdd(&cnt_in[in_rows[e]], 1);
    else         atomicAdd(&cnt_rec[rec_cols[e - EIN]], 1);
  }
}

// ---------- 3-phase exclusive scan ----------
__global__ __launch_bounds__(SCAN_TPB) void blocksum_k(const int* __restrict__ cnt, int n,
                                                       int* __restrict__ partial) {
  __shared__ int sm[SCAN_TPB];
  int base = (blockIdx.x * SCAN_TPB + threadIdx.x) * SCAN_ITEMS;
  int s = 0;
  #pragma unroll
  for (int j = 0; j < SCAN_ITEMS; ++j) { int idx = base + j; if (idx < n) s += cnt[idx]; }
  sm[threadIdx.x] = s; __syncthreads();
  for (int off = SCAN_TPB / 2; off > 0; off >>= 1) {
    if (threadIdx.x < off) sm[threadIdx.x] += sm[threadIdx.x + off];
    __syncthreads();
  }
  if (threadIdx.x == 0) partial[blockIdx.x] = sm[0];
}

__global__ __launch_bounds__(SCAN_TPB) void scanpart_k(int* __restrict__ partial, int nb) {
  __shared__ int sm[SCAN_TPB];
  int i = threadIdx.x;
  int v = (i < nb) ? partial[i] : 0;
  sm[i] = v; __syncthreads();
  for (int off = 1; off < SCAN_TPB; off <<= 1) {
    int a = (i >= off) ? sm[i - off] : 0;
    __syncthreads();
    sm[i] += a;
    __syncthreads();
  }
  if (i < nb) partial[i] = sm[i] - v;   // exclusive
}

__global__ __launch_bounds__(SCAN_TPB) void finalize_k(const int* __restrict__ cnt, int n,
                                                       const int* __restrict__ partial,
                                                       int* __restrict__ ptr,
                                                       int* __restrict__ cursor, int nE) {
  __shared__ int sm[SCAN_TPB];
  int tidl = threadIdx.x;
  int base = (blockIdx.x * SCAN_TPB + tidl) * SCAN_ITEMS;
  int local[SCAN_ITEMS];
  int s = 0;
  #pragma unroll
  for (int j = 0; j < SCAN_ITEMS; ++j) {
    int idx = base + j;
    int c = (idx < n) ? cnt[idx] : 0;
    local[j] = c; s += c;
  }
  sm[tidl] = s; __syncthreads();
  for (int off = 1; off < SCAN_TPB; off <<= 1) {
    int a = (tidl >= off) ? sm[tidl - off] : 0;
    __syncthreads();
    sm[tidl] += a;
    __syncthreads();
  }
  int run = partial[blockIdx.x] + sm[tidl] - s;
  #pragma unroll
  for (int j = 0; j < SCAN_ITEMS; ++j) {
    int idx = base + j;
    if (idx < n) { ptr[idx] = run; cursor[idx] = run; run += local[j]; }
  }
  if (blockIdx.x == 0 && tidl == 0) ptr[n] = nE;
}

// ---------- fused scatter (build CSR/CSC payloads) ----------
__global__ void scatter2_k(const int* __restrict__ in_rows, const int* __restrict__ in_cols,
                           const float* __restrict__ in_w,
                           const int* __restrict__ rec_cols, const int* __restrict__ rec_rows,
                           const float* __restrict__ rec_w,
                           int* __restrict__ cur_in, int* __restrict__ cur_rec,
                           int2* __restrict__ cw_in, int2* __restrict__ cw_rec) {
  int i = blockIdx.x * blockDim.x + threadIdx.x;
  int nth = gridDim.x * blockDim.x;
  for (int e = i; e < EIN + EREC; e += nth) {
    if (e < EIN) {
      int pos = atomicAdd(&cur_in[in_rows[e]], 1);
      cw_in[pos] = make_int2(in_cols[e], __float_as_int(in_w[e]));
    } else {
      int ee = e - EIN;
      int pos = atomicAdd(&cur_rec[rec_cols[ee]], 1);
      cw_rec[pos] = make_int2(rec_rows[ee], __float_as_int(rec_w[ee]));
    }
  }
}

// ---------- input-current precompute: 100 independent (t,b) slices ----------
__global__ __launch_bounds__(256) void precomp_k(const float* __restrict__ x,
                                                 const int* __restrict__ rest,
                                                 const float* __restrict__ bkg,
                                                 const int* __restrict__ row_ptr,
                                                 const int2* __restrict__ cw,
                                                 float* __restrict__ ic) {
  int n  = blockIdx.x * blockDim.x + threadIdx.x;   // neuron
  int tb = blockIdx.y;                              // t*BB + b
  if (n >= NN) return;
  int t = tb >> 1, b = tb & 1;                      // BB == 2
  const float* xt = x + ((size_t)b * TT + t) * NIN;
  float restf = (float)rest[tb] * 0.1f;             // rest[(t,b)] layout (T,B)
  int rp[RR + 1];
  #pragma unroll
  for (int r = 0; r <= RR; ++r) rp[r] = row_ptr[n * RR + r];
  float o[RR];
  #pragma unroll
  for (int r = 0; r < RR; ++r) {
    float acc = bkg[n * RR + r] * restf;
    for (int e = rp[r]; e < rp[r + 1]; ++e) {
      int2 c = cw[e];
      acc += xt[c.x] * __int_as_float(c.y);
    }
    o[r] = acc;
  }
  *(float4*)(ic + (size_t)tb * RNN + (size_t)n * RR) =
      make_float4(o[0], o[1], o[2], o[3]);
}

// ---------- main persistent kernel ----------
__global__ __launch_bounds__(1024, 1) void snn_all(SP p) {
  cg::grid_group grid = cg::this_grid();
  const int tid = blockIdx.x * blockDim.x + threadIdx.x;

  const bool owner = tid < BB * NN;
  int b = 0, n = 0;
  float sd[RR], pi[RR], bkgv[RR], psc_rise[RR], psc[RR];
  int rbeg[RR], rend[RR];
  float v = 0.f, refr = 0.f, a1 = 0.f, a2 = 0.f, my_z = 0.f;
  float dcy = 0.f, cfac = 0.f, trf = 0.f, amp1 = 0.f, amp2 = 0.f;
  float ad1 = 0.f, ad2 = 0.f, vth = 0.f, invn = 0.f, leak = 0.f;
  float vrst = 0.f, vsc = 0.f, vof = 0.f;
  #pragma unroll
  for (int r = 0; r < RR; ++r) {
    sd[r]=0.f; pi[r]=0.f; bkgv[r]=0.f; psc_rise[r]=0.f; psc[r]=0.f;
    rbeg[r]=0; rend[r]=0;
  }

  if (owner) {
    b = (tid >= NN) ? 1 : 0;
    n = tid - b * NN;
    #pragma unroll
    for (int r = 0; r < RR; ++r) {
      sd[r] = p.syn_decay[n*RR + r];
      pi[r] = p.psc_init[n*RR + r];
    }
    if (!p.in_cur) {
      #pragma unroll
      for (int r = 0; r < RR; ++r) {
        bkgv[r] = p.bkg[n*RR + r];
        rbeg[r] = p.row_ptr[n*RR + r];
        rend[r] = p.row_ptr[n*RR + r + 1];
      }
    }
    vth  = p.v_th[n];
    float el = p.e_l[n];
    invn = 1.0f / (vth - el);
    leak = p.g[n] * el;
    vrst = p.v_reset[n];
    v    = vrst;
    dcy  = p.decay[n];
    cfac = p.cf[n];
    trf  = p.t_ref[n];
    amp1 = p.asc_amps[2*n+0];
    amp2 = p.asc_amps[2*n+1];
    ad1  = expf(-p.param_k[2*n+0]);
    ad2  = expf(-p.param_k[2*n+1]);
    vsc  = p.vscale[n];
    vof  = p.voff[n];
  }
  const float* xb = p.x + (size_t)b * TT * NIN;
  float* ringB = p.cur_ring + (size_t)b * RING * RNN;

  for (int t = 0; t < TT; ++t) {
    if (t) grid.sync();   // ring pushes + flags from step t-1 now visible

    if (owner) {
      int slot = t % RING;
      float rin[RR];

      if (p.in_cur) {
        const float4 iv = *(const float4*)(p.in_cur + (size_t)(t*BB + b) * RNN + (size_t)n * RR);
        rin[0] = iv.x; rin[1] = iv.y; rin[2] = iv.z; rin[3] = iv.w;
      } else {
        float restf = (float)p.rest[t*BB + b] * 0.1f;
        const float* xt = xb + (size_t)t * NIN;
        #pragma unroll
        for (int r = 0; r < RR; ++r) {
          float acc = bkgv[r] * restf;
          for (int e = rbeg[r]; e < rend[r]; ++e) {
            int2 cw = p.cw_in[e];
            acc += xt[cw.x] * __int_as_float(cw.y);
          }
          rin[r] = acc;
        }
      }

      // recurrent ring slot: read+zero only when epoch tag matches this step
      if (p.flags[b*RING + slot] == t) {
        float4* slotR = (float4*)(ringB + (size_t)slot * RNN);
        float4 rv = slotR[n];
        slotR[n] = make_float4(0.f, 0.f, 0.f, 0.f);   // reused at step t+RING
        rin[0] += rv.x; rin[1] += rv.y; rin[2] += rv.z; rin[3] += rv.w;
      }

      float prev_z = my_z;
      float input_current = psc[0] + psc[1] + psc[2] + psc[3];   // OLD psc
      float new_v = dcy * v + cfac * (input_current + a1 + a2 + leak)
                    + prev_z * (vrst - vth);
      #pragma unroll
      for (int r = 0; r < RR; ++r) {       // new_psc uses OLD psc_rise
        float npsc = psc[r] * sd[r] + sd[r] * psc_rise[r];
        psc_rise[r] = sd[r] * psc_rise[r] + rin[r] * pi[r];
        psc[r] = npsc;
      }
      refr = fmaxf(refr + prev_z * trf - 1.0f, 0.f);
      a1 = ad1 * a1 + prev_z * amp1;
      a2 = ad2 * a2 + prev_z * amp2;
      v = new_v;
      float v_scaled = (new_v - vth) * invn;
      float z = (v_scaled > 0.f) ? 1.f : 0.f;
      if (refr > 0.f) z = 0.f;
      my_z = z;
      size_t oidx = (size_t)b * (TT*NN) + (size_t)t * NN + n;
      p.out_z[oidx] = z;
      p.out_v[oidx] = new_v * vsc + vof;

      // event-driven scatter: push outgoing edges into future ring slots
      if (z != 0.f) {
        #pragma unroll
        for (int d = 0; d < DDEP; ++d) {
          int tt = t + 1 + d;
          if (tt >= TT) break;
          int col = d * NN + n;
          int be = p.col_ptr[col], en = p.col_ptr[col + 1];
          if (be != en) {
            int ws_ = tt % RING;
            p.flags[b*RING + ws_] = tt;   // benign same-value race; fenced by grid.sync
            float* ringW = ringB + (size_t)ws_ * RNN;
            for (int e = be; e < en; ++e) {
              int2 cw = p.cw_rec[e];
              atomicAdd(&ringW[cw.x], __int_as_float(cw.y));
            }
          }
        }
      }
    }
  }
}

extern "C" void kernel_launch(void* const* d_in, const int* in_sizes, int n_in,
                              void* d_out, int out_size, void* d_ws, size_t ws_size,
                              hipStream_t stream) {
  SP p;
  p.x        = (const float*)d_in[0];
  const float* rec_w = (const float*)d_in[1];
  const float* in_w  = (const float*)d_in[2];
  p.bkg      = (const float*)d_in[3];
  p.v_th     = (const float*)d_in[4];
  p.e_l      = (const float*)d_in[5];
  p.v_reset  = (const float*)d_in[6];
  p.g        = (const float*)d_in[7];
  p.t_ref    = (const float*)d_in[8];
  p.asc_amps = (const float*)d_in[9];
  p.param_k  = (const float*)d_in[10];
  p.decay    = (const float*)d_in[11];
  p.cf       = (const float*)d_in[12];
  p.syn_decay= (const float*)d_in[13];
  p.psc_init = (const float*)d_in[14];
  p.vscale   = (const float*)d_in[15];
  p.voff     = (const float*)d_in[16];
  const int* rec_rows = (const int*)d_in[17];
  const int* rec_cols = (const int*)d_in[18];
  const int* in_rows  = (const int*)d_in[19];
  const int* in_cols  = (const int*)d_in[20];
  p.rest     = (const int*)d_in[21];
  p.out_z = (float*)d_out;
  p.out_v = (float*)d_out + (size_t)BB * TT * NN;

  // ---- workspace layout ----
  char* ws = (char*)d_ws;
  size_t off = 0;
  auto alloc = [&](size_t bytes) { void* q = ws + off; off += (bytes + 255) & ~(size_t)255; return q; };
  float* cur_ring = (float*)alloc(sizeof(float) * (size_t)BB * RING * RNN); // 9.6 MB
  int*   flags    = (int*)  alloc(sizeof(int) * BB * RING);
  int*   row_ptr  = (int*)  alloc(sizeof(int) * ((size_t)RNN + 1));
  int*   col_ptr  = (int*)  alloc(sizeof(int) * ((size_t)DNN + 1));
  int*   cnt_in   = (int*)  alloc(sizeof(int) * (size_t)RNN);
  int*   cnt_rec  = (int*)  alloc(sizeof(int) * (size_t)DNN);
  int*   cur_in   = (int*)  alloc(sizeof(int) * (size_t)RNN);
  int*   cur_rec  = (int*)  alloc(sizeof(int) * (size_t)DNN);
  int*   part_in  = (int*)  alloc(sizeof(int) * SCAN_TPB);
  int*   part_rec = (int*)  alloc(sizeof(int) * SCAN_TPB);
  int2*  cw_in    = (int2*) alloc(sizeof(int2) * (size_t)EIN);              // 4 MB
  int2*  cw_rec   = (int2*) alloc(sizeof(int2) * (size_t)EREC);             // 16 MB
  float* in_cur   = (float*)alloc(sizeof(float) * (size_t)TT * BB * RNN);   // 80 MB
  const bool use_pre = (off <= ws_size);

  p.cur_ring = cur_ring; p.flags = flags;
  p.row_ptr = row_ptr; p.cw_in = cw_in;
  p.col_ptr = col_ptr; p.cw_rec = cw_rec;
  p.in_cur = use_pre ? in_cur : nullptr;

  hipMemsetAsync(cur_ring, 0, sizeof(float) * (size_t)BB * RING * RNN, stream);
  hipMemsetAsync(flags, 0xFF, sizeof(int) * BB * RING, stream);            // -1 epochs
  hipMemsetAsync(cnt_in, 0, sizeof(int) * (size_t)RNN, stream);
  hipMemsetAsync(cnt_rec, 0, sizeof(int) * (size_t)DNN, stream);

  hipLaunchKernelGGL(hist2_k, dim3(1024), dim3(256), 0, stream,
                     in_rows, rec_cols, cnt_in, cnt_rec);

  const int NB_IN  = (RNN + SCAN_TPB * SCAN_ITEMS - 1) / (SCAN_TPB * SCAN_ITEMS);  // 196
  const int NB_REC = (DNN + SCAN_TPB * SCAN_ITEMS - 1) / (SCAN_TPB * SCAN_ITEMS);  // 245
  hipLaunchKernelGGL(blocksum_k, dim3(NB_IN),  dim3(SCAN_TPB), 0, stream, cnt_in,  RNN, part_in);
  hipLaunchKernelGGL(blocksum_k, dim3(NB_REC), dim3(SCAN_TPB), 0, stream, cnt_rec, DNN, part_rec);
  hipLaunchKernelGGL(scanpart_k, dim3(1), dim3(SCAN_TPB), 0, stream, part_in,  NB_IN);
  hipLaunchKernelGGL(scanpart_k, dim3(1), dim3(SCAN_TPB), 0, stream, part_rec, NB_REC);
  hipLaunchKernelGGL(finalize_k, dim3(NB_IN),  dim3(SCAN_TPB), 0, stream, cnt_in,  RNN, part_in,  row_ptr, cur_in,  EIN);
  hipLaunchKernelGGL(finalize_k, dim3(NB_REC), dim3(SCAN_TPB), 0, stream, cnt_rec, DNN, part_rec, col_ptr, cur_rec, EREC);

  hipLaunchKernelGGL(scatter2_k, dim3(1024), dim3(256), 0, stream,
                     in_rows, in_cols, in_w, rec_cols, rec_rows, rec_w,
                     cur_in, cur_rec, cw_in, cw_rec);

  if (use_pre) {
    hipLaunchKernelGGL(precomp_k, dim3((NN + 255) / 256, TT * BB), dim3(256), 0, stream,
                       p.x, p.rest, p.bkg, row_ptr, cw_in, in_cur);
  }

  void* args[] = { (void*)&p };
  hipLaunchCooperativeKernel(reinterpret_cast<const void*>(&snn_all),
                             dim3(104), dim3(1024), args, 0u, stream);
}

// Round 6
// 835.089 us; speedup vs baseline: 4.1091x; 1.6988x over previous
//
#include <hip/hip_runtime.h>
#include <hip/hip_cooperative_groups.h>

namespace cg = cooperative_groups;

#define NN    50000
#define RR    4
#define DDEP  5
#define NIN   17400
#define BB    2
#define TT    50
#define EREC  2000000
#define EIN   500000
#define RNN   (RR*NN)    // 200000
#define DNN   (DDEP*NN)  // 250000
#define RING  6
#define TB    (TT*BB)    // 100
#define CH    20         // (t,b) slices per precomp chunk
#define NCH   (TB/CH)    // 5
#define SCAN_TPB 256
#define SCAN_ITEMS 4

struct SP {
  const float* x; const float* bkg;
  const float* v_th; const float* e_l; const float* v_reset; const float* g;
  const float* t_ref; const float* asc_amps; const float* param_k;
  const float* decay; const float* cf; const float* syn_decay; const float* psc_init;
  const float* vscale; const float* voff;
  const int* rest;
  float* out_z; float* out_v;
  float* cur_ring;      // ws: [BB][RING][RNN]
  int*   flags;         // ws: [BB][RING] epoch tags
  int*   bar;           // ws: [64] {cnt @0, gen @32}
  const int* row_ptr;   // ws: [RNN+1]  input CSR
  const int2* cw_in;    // ws: [EIN]   {col, w-bits}
  const int* col_ptr;   // ws: [DNN+1]  rec CSC
  const int2* cw_rec;   // ws: [EREC]  {row, w-bits}
  const float* in_cur;  // ws: [TB][RNN] precomputed input currents (or nullptr)
};

// ---------- fused histogram ----------
__global__ void hist2_k(const int* __restrict__ in_rows, const int* __restrict__ rec_cols,
                        int* __restrict__ cnt_in, int* __restrict__ cnt_rec) {
  int i = blockIdx.x * blockDim.x + threadIdx.x;
  int nth = gridDim.x * blockDim.x;
  for (int e = i; e < EIN + EREC; e += nth) {
    if (e < EIN) atomicAdd(&cnt_in[in_rows[e]], 1);
    else         atomicAdd(&cnt_rec[rec_cols[e - EIN]], 1);
  }
}

// ---------- 3-phase exclusive scan ----------
__global__ __launch_bounds__(SCAN_TPB) void blocksum_k(const int* __restrict__ cnt, int n,
                                                       int* __restrict__ partial) {
  __shared__ int sm[SCAN_TPB];
  int base = (blockIdx.x * SCAN_TPB + threadIdx.x) * SCAN_ITEMS;
  int s = 0;
  #pragma unroll
  for (int j = 0; j < SCAN_ITEMS; ++j) { int idx = base + j; if (idx < n) s += cnt[idx]; }
  sm[threadIdx.x] = s; __syncthreads();
  for (int off = SCAN_TPB / 2; off > 0; off >>= 1) {
    if (threadIdx.x < off) sm[threadIdx.x] += sm[threadIdx.x + off];
    __syncthreads();
  }
  if (threadIdx.x == 0) partial[blockIdx.x] = sm[0];
}

__global__ __launch_bounds__(SCAN_TPB) void scanpart_k(int* __restrict__ partial, int nb) {
  __shared__ int sm[SCAN_TPB];
  int i = threadIdx.x;
  int v = (i < nb) ? partial[i] : 0;
  sm[i] = v; __syncthreads();
  for (int off = 1; off < SCAN_TPB; off <<= 1) {
    int a = (i >= off) ? sm[i - off] : 0;
    __syncthreads();
    sm[i] += a;
    __syncthreads();
  }
  if (i < nb) partial[i] = sm[i] - v;
}

__global__ __launch_bounds__(SCAN_TPB) void finalize_k(const int* __restrict__ cnt, int n,
                                                       const int* __restrict__ partial,
                                                       int* __restrict__ ptr,
                                                       int* __restrict__ cursor, int nE) {
  __shared__ int sm[SCAN_TPB];
  int tidl = threadIdx.x;
  int base = (blockIdx.x * SCAN_TPB + tidl) * SCAN_ITEMS;
  int local[SCAN_ITEMS];
  int s = 0;
  #pragma unroll
  for (int j = 0; j < SCAN_ITEMS; ++j) {
    int idx = base + j;
    int c = (idx < n) ? cnt[idx] : 0;
    local[j] = c; s += c;
  }
  sm[tidl] = s; __syncthreads();
  for (int off = 1; off < SCAN_TPB; off <<= 1) {
    int a = (tidl >= off) ? sm[tidl - off] : 0;
    __syncthreads();
    sm[tidl] += a;
    __syncthreads();
  }
  int run = partial[blockIdx.x] + sm[tidl] - s;
  #pragma unroll
  for (int j = 0; j < SCAN_ITEMS; ++j) {
    int idx = base + j;
    if (idx < n) { ptr[idx] = run; cursor[idx] = run; run += local[j]; }
  }
  if (blockIdx.x == 0 && tidl == 0) ptr[n] = nE;
}

// ---------- fused scatter (build CSR/CSC payloads) ----------
__global__ void scatter2_k(const int* __restrict__ in_rows, const int* __restrict__ in_cols,
                           const float* __restrict__ in_w,
                           const int* __restrict__ rec_cols, const int* __restrict__ rec_rows,
                           const float* __restrict__ rec_w,
                           int* __restrict__ cur_in, int* __restrict__ cur_rec,
                           int2* __restrict__ cw_in, int2* __restrict__ cw_rec) {
  int i = blockIdx.x * blockDim.x + threadIdx.x;
  int nth = gridDim.x * blockDim.x;
  for (int e = i; e < EIN + EREC; e += nth) {
    if (e < EIN) {
      int pos = atomicAdd(&cur_in[in_rows[e]], 1);
      cw_in[pos] = make_int2(in_cols[e], __float_as_int(in_w[e]));
    } else {
      int ee = e - EIN;
      int pos = atomicAdd(&cur_rec[rec_cols[ee]], 1);
      cw_rec[pos] = make_int2(rec_rows[ee], __float_as_int(rec_w[ee]));
    }
  }
}

// ---------- x transpose: x[b][t][c] -> xT[c][t*2+b] ----------
__global__ __launch_bounds__(256) void xpose_k(const float* __restrict__ x,
                                               float* __restrict__ xT) {
  __shared__ float tile[64][TB + 1];
  int c0 = blockIdx.x * 64;
  int cl = threadIdx.x & 63;
  for (int tb = threadIdx.x >> 6; tb < TB; tb += 4) {
    int t = tb >> 1, b = tb & 1;
    int c = c0 + cl;
    tile[cl][tb] = (c < NIN) ? x[((size_t)b * TT + t) * NIN + c] : 0.f;
  }
  __syncthreads();
  int cc = threadIdx.x >> 2;          // 0..63
  int seg = (threadIdx.x & 3) * (TB / 4);
  int c = c0 + cc;
  if (c < NIN) {
    for (int j = seg; j < seg + TB / 4; ++j)
      xT[(size_t)c * TB + j] = tile[cc][j];
  }
}

// ---------- slice-vectorized input-current precompute ----------
__global__ __launch_bounds__(256) void precomp2_k(const float* __restrict__ xT,
                                                  const int* __restrict__ rest,
                                                  const float* __restrict__ bkg,
                                                  const int* __restrict__ row_ptr,
                                                  const int2* __restrict__ cw,
                                                  float* __restrict__ ic) {
  const int nbn = (NN + 255) >> 8;            // 196
  int chunk = blockIdx.x / nbn;
  int n = (blockIdx.x % nbn) * 256 + threadIdx.x;
  if (n >= NN) return;
  const int tb0 = chunk * CH;

  float restf[CH];
  #pragma unroll
  for (int j = 0; j < CH; ++j) restf[j] = (float)rest[tb0 + j] * 0.1f;

  int rp[RR + 1];
  #pragma unroll
  for (int r = 0; r <= RR; ++r) rp[r] = row_ptr[n * RR + r];

  float acc[RR][CH];
  #pragma unroll
  for (int r = 0; r < RR; ++r) {
    float bk = bkg[n * RR + r];
    #pragma unroll
    for (int j = 0; j < CH; ++j) acc[r][j] = bk * restf[j];
    for (int e = rp[r]; e < rp[r + 1]; ++e) {
      int2 c = cw[e];
      float w = __int_as_float(c.y);
      const float* xr = xT + (size_t)c.x * TB + tb0;
      #pragma unroll
      for (int j = 0; j < CH; ++j) acc[r][j] += w * xr[j];
    }
  }
  #pragma unroll
  for (int j = 0; j < CH; ++j) {
    *(float4*)(ic + (size_t)(tb0 + j) * RNN + (size_t)n * RR) =
        make_float4(acc[0][j], acc[1][j], acc[2][j], acc[3][j]);
  }
}

// ---------- lean grid barrier (sense via monotonically increasing gen) ----------
__device__ __forceinline__ void gridbar(int* bar, int nb, int target) {
  __syncthreads();   // drains vmcnt: all block's writes are in L2
  if (threadIdx.x == 0) {
    int* cnt = bar;
    int* gen = bar + 32;
    int old = __hip_atomic_fetch_add(cnt, 1, __ATOMIC_ACQ_REL, __HIP_MEMORY_SCOPE_AGENT);
    if (old == nb - 1) {
      __hip_atomic_store(cnt, 0, __ATOMIC_RELAXED, __HIP_MEMORY_SCOPE_AGENT);
      __hip_atomic_store(gen, target, __ATOMIC_RELEASE, __HIP_MEMORY_SCOPE_AGENT);
    } else {
      while (__hip_atomic_load(gen, __ATOMIC_RELAXED, __HIP_MEMORY_SCOPE_AGENT) < target)
        __builtin_amdgcn_s_sleep(2);
      (void)__hip_atomic_load(gen, __ATOMIC_ACQUIRE, __HIP_MEMORY_SCOPE_AGENT);
    }
  }
  __syncthreads();
}

// ---------- main persistent kernel ----------
__global__ __launch_bounds__(1024, 1) void snn_all(SP p) {
  const int tid = blockIdx.x * blockDim.x + threadIdx.x;
  const int nb = gridDim.x;

  const bool owner = tid < BB * NN;
  int b = 0, n = 0;
  float sd[RR], pi[RR], bkgv[RR], psc_rise[RR], psc[RR];
  int rbeg[RR], rend[RR];
  float v = 0.f, refr = 0.f, a1 = 0.f, a2 = 0.f, my_z = 0.f;
  float dcy = 0.f, cfac = 0.f, trf = 0.f, amp1 = 0.f, amp2 = 0.f;
  float ad1 = 0.f, ad2 = 0.f, vth = 0.f, invn = 0.f, leak = 0.f;
  float vrst = 0.f, vsc = 0.f, vof = 0.f;
  #pragma unroll
  for (int r = 0; r < RR; ++r) {
    sd[r]=0.f; pi[r]=0.f; bkgv[r]=0.f; psc_rise[r]=0.f; psc[r]=0.f;
    rbeg[r]=0; rend[r]=0;
  }

  if (owner) {
    b = (tid >= NN) ? 1 : 0;
    n = tid - b * NN;
    #pragma unroll
    for (int r = 0; r < RR; ++r) {
      sd[r] = p.syn_decay[n*RR + r];
      pi[r] = p.psc_init[n*RR + r];
    }
    if (!p.in_cur) {
      #pragma unroll
      for (int r = 0; r < RR; ++r) {
        bkgv[r] = p.bkg[n*RR + r];
        rbeg[r] = p.row_ptr[n*RR + r];
        rend[r] = p.row_ptr[n*RR + r + 1];
      }
    }
    vth  = p.v_th[n];
    float el = p.e_l[n];
    invn = 1.0f / (vth - el);
    leak = p.g[n] * el;
    vrst = p.v_reset[n];
    v    = vrst;
    dcy  = p.decay[n];
    cfac = p.cf[n];
    trf  = p.t_ref[n];
    amp1 = p.asc_amps[2*n+0];
    amp2 = p.asc_amps[2*n+1];
    ad1  = expf(-p.param_k[2*n+0]);
    ad2  = expf(-p.param_k[2*n+1]);
    vsc  = p.vscale[n];
    vof  = p.voff[n];
  }
  const float* xb = p.x + (size_t)b * TT * NIN;
  float* ringB = p.cur_ring + (size_t)b * RING * RNN;

  // prefetch step-0 input current
  float4 iv = make_float4(0.f, 0.f, 0.f, 0.f);
  if (owner && p.in_cur)
    iv = *(const float4*)(p.in_cur + (size_t)b * RNN + (size_t)n * RR);

  for (int t = 0; t < TT; ++t) {
    if (t) gridbar(p.bar, nb, t);   // ring pushes + flags from step t-1 now visible

    if (owner) {
      int slot = t % RING;
      float rin[RR];

      if (p.in_cur) {
        rin[0] = iv.x; rin[1] = iv.y; rin[2] = iv.z; rin[3] = iv.w;
      } else {
        float restf = (float)p.rest[t*BB + b] * 0.1f;
        const float* xt = xb + (size_t)t * NIN;
        #pragma unroll
        for (int r = 0; r < RR; ++r) {
          float acc = bkgv[r] * restf;
          for (int e = rbeg[r]; e < rend[r]; ++e) {
            int2 cw = p.cw_in[e];
            acc += xt[cw.x] * __int_as_float(cw.y);
          }
          rin[r] = acc;
        }
      }

      // recurrent ring slot: read+zero only when epoch tag matches this step
      if (p.flags[b*RING + slot] == t) {
        float4* slotR = (float4*)(ringB + (size_t)slot * RNN);
        float4 rv = slotR[n];
        slotR[n] = make_float4(0.f, 0.f, 0.f, 0.f);
        rin[0] += rv.x; rin[1] += rv.y; rin[2] += rv.z; rin[3] += rv.w;
      }

      float prev_z = my_z;
      float input_current = psc[0] + psc[1] + psc[2] + psc[3];   // OLD psc
      float new_v = dcy * v + cfac * (input_current + a1 + a2 + leak)
                    + prev_z * (vrst - vth);
      #pragma unroll
      for (int r = 0; r < RR; ++r) {       // new_psc uses OLD psc_rise
        float npsc = psc[r] * sd[r] + sd[r] * psc_rise[r];
        psc_rise[r] = sd[r] * psc_rise[r] + rin[r] * pi[r];
        psc[r] = npsc;
      }
      refr = fmaxf(refr + prev_z * trf - 1.0f, 0.f);
      a1 = ad1 * a1 + prev_z * amp1;
      a2 = ad2 * a2 + prev_z * amp2;
      v = new_v;
      float v_scaled = (new_v - vth) * invn;
      float z = (v_scaled > 0.f) ? 1.f : 0.f;
      if (refr > 0.f) z = 0.f;
      my_z = z;
      size_t oidx = (size_t)b * (TT*NN) + (size_t)t * NN + n;
      p.out_z[oidx] = z;
      p.out_v[oidx] = new_v * vsc + vof;

      // event-driven scatter into future ring slots
      if (z != 0.f) {
        #pragma unroll
        for (int d = 0; d < DDEP; ++d) {
          int tt = t + 1 + d;
          if (tt >= TT) break;
          int col = d * NN + n;
          int be = p.col_ptr[col], en = p.col_ptr[col + 1];
          if (be != en) {
            int ws_ = tt % RING;
            p.flags[b*RING + ws_] = tt;   // benign same-value race
            float* ringW = ringB + (size_t)ws_ * RNN;
            for (int e = be; e < en; ++e) {
              int2 cw = p.cw_rec[e];
              atomicAdd(&ringW[cw.x], __int_as_float(cw.y));
            }
          }
        }
      }

      // prefetch next step's input current (hides under barrier wait)
      if (p.in_cur && t + 1 < TT)
        iv = *(const float4*)(p.in_cur + (size_t)((t+1)*BB + b) * RNN + (size_t)n * RR);
    }
  }
}

extern "C" void kernel_launch(void* const* d_in, const int* in_sizes, int n_in,
                              void* d_out, int out_size, void* d_ws, size_t ws_size,
                              hipStream_t stream) {
  SP p;
  p.x        = (const float*)d_in[0];
  const float* rec_w = (const float*)d_in[1];
  const float* in_w  = (const float*)d_in[2];
  p.bkg      = (const float*)d_in[3];
  p.v_th     = (const float*)d_in[4];
  p.e_l      = (const float*)d_in[5];
  p.v_reset  = (const float*)d_in[6];
  p.g        = (const float*)d_in[7];
  p.t_ref    = (const float*)d_in[8];
  p.asc_amps = (const float*)d_in[9];
  p.param_k  = (const float*)d_in[10];
  p.decay    = (const float*)d_in[11];
  p.cf       = (const float*)d_in[12];
  p.syn_decay= (const float*)d_in[13];
  p.psc_init = (const float*)d_in[14];
  p.vscale   = (const float*)d_in[15];
  p.voff     = (const float*)d_in[16];
  const int* rec_rows = (const int*)d_in[17];
  const int* rec_cols = (const int*)d_in[18];
  const int* in_rows  = (const int*)d_in[19];
  const int* in_cols  = (const int*)d_in[20];
  p.rest     = (const int*)d_in[21];
  p.out_z = (float*)d_out;
  p.out_v = (float*)d_out + (size_t)BB * TT * NN;

  // ---- workspace layout ----
  char* ws = (char*)d_ws;
  size_t off = 0;
  auto alloc = [&](size_t bytes) { void* q = ws + off; off += (bytes + 255) & ~(size_t)255; return q; };
  float* cur_ring = (float*)alloc(sizeof(float) * (size_t)BB * RING * RNN); // 9.6 MB
  int*   flags    = (int*)  alloc(sizeof(int) * BB * RING);
  int*   bar      = (int*)  alloc(sizeof(int) * 64);
  int*   row_ptr  = (int*)  alloc(sizeof(int) * ((size_t)RNN + 1));
  int*   col_ptr  = (int*)  alloc(sizeof(int) * ((size_t)DNN + 1));
  int*   cnt_in   = (int*)  alloc(sizeof(int) * (size_t)RNN);
  int*   cnt_rec  = (int*)  alloc(sizeof(int) * (size_t)DNN);
  int*   cur_in   = (int*)  alloc(sizeof(int) * (size_t)RNN);
  int*   cur_rec  = (int*)  alloc(sizeof(int) * (size_t)DNN);
  int*   part_in  = (int*)  alloc(sizeof(int) * SCAN_TPB);
  int*   part_rec = (int*)  alloc(sizeof(int) * SCAN_TPB);
  int2*  cw_in    = (int2*) alloc(sizeof(int2) * (size_t)EIN);              // 4 MB
  int2*  cw_rec   = (int2*) alloc(sizeof(int2) * (size_t)EREC);             // 16 MB
  float* xT       = (float*)alloc(sizeof(float) * (size_t)NIN * TB);        // 7 MB
  float* in_cur   = (float*)alloc(sizeof(float) * (size_t)TB * RNN);        // 80 MB
  const bool use_pre = (off <= ws_size);

  p.cur_ring = cur_ring; p.flags = flags; p.bar = bar;
  p.row_ptr = row_ptr; p.cw_in = cw_in;
  p.col_ptr = col_ptr; p.cw_rec = cw_rec;
  p.in_cur = use_pre ? in_cur : nullptr;

  hipMemsetAsync(cur_ring, 0, sizeof(float) * (size_t)BB * RING * RNN, stream);
  hipMemsetAsync(flags, 0xFF, sizeof(int) * BB * RING, stream);   // -1 epochs
  hipMemsetAsync(bar, 0, sizeof(int) * 64, stream);
  hipMemsetAsync(cnt_in, 0, sizeof(int) * (size_t)RNN, stream);
  hipMemsetAsync(cnt_rec, 0, sizeof(int) * (size_t)DNN, stream);

  hipLaunchKernelGGL(hist2_k, dim3(1024), dim3(256), 0, stream,
                     in_rows, rec_cols, cnt_in, cnt_rec);

  const int NB_IN  = (RNN + SCAN_TPB * SCAN_ITEMS - 1) / (SCAN_TPB * SCAN_ITEMS);  // 196
  const int NB_REC = (DNN + SCAN_TPB * SCAN_ITEMS - 1) / (SCAN_TPB * SCAN_ITEMS);  // 245
  hipLaunchKernelGGL(blocksum_k, dim3(NB_IN),  dim3(SCAN_TPB), 0, stream, cnt_in,  RNN, part_in);
  hipLaunchKernelGGL(blocksum_k, dim3(NB_REC), dim3(SCAN_TPB), 0, stream, cnt_rec, DNN, part_rec);
  hipLaunchKernelGGL(scanpart_k, dim3(1), dim3(SCAN_TPB), 0, stream, part_in,  NB_IN);
  hipLaunchKernelGGL(scanpart_k, dim3(1), dim3(SCAN_TPB), 0, stream, part_rec, NB_REC);
  hipLaunchKernelGGL(finalize_k, dim3(NB_IN),  dim3(SCAN_TPB), 0, stream, cnt_in,  RNN, part_in,  row_ptr, cur_in,  EIN);
  hipLaunchKernelGGL(finalize_k, dim3(NB_REC), dim3(SCAN_TPB), 0, stream, cnt_rec, DNN, part_rec, col_ptr, cur_rec, EREC);

  hipLaunchKernelGGL(scatter2_k, dim3(1024), dim3(256), 0, stream,
                     in_rows, in_cols, in_w, rec_cols, rec_rows, rec_w,
                     cur_in, cur_rec, cw_in, cw_rec);

  if (use_pre) {
    hipLaunchKernelGGL(xpose_k, dim3((NIN + 63) / 64), dim3(256), 0, stream, p.x, xT);
    const int nbn = (NN + 255) / 256;  // 196
    hipLaunchKernelGGL(precomp2_k, dim3(nbn * NCH), dim3(256), 0, stream,
                       xT, p.rest, p.bkg, row_ptr, cw_in, in_cur);
  }

  void* args[] = { (void*)&p };
  hipLaunchCooperativeKernel(reinterpret_cast<const void*>(&snn_all),
                             dim3(104), dim3(1024), args, 0u, stream);
}